// Round 11
// baseline (294.295 us; speedup 1.0000x reference)
//
#include <hip/hip_runtime.h>
#include <hip/hip_bf16.h>
#include <stdint.h>

#define WW    361    // W*W spatial positions
#define CCH   64     // channels (K)
#define NQR   368    // Q rows padded to 23 tiles of 16
#define NT    23
#define NTHR  512    // 8 waves
#define WWC   (WW*CCH)

typedef __attribute__((ext_vector_type(8))) short short8;
typedef __attribute__((ext_vector_type(4))) float f32x4;

// R11: traffic-minimal single-pass. Session model (calibrated on R0..R10):
// every structure delivers 3.4-4.4 TB/s; dur = traffic/BW. So read each
// input byte exactly ONCE: one block per bs (600 blocks, 512 thr), full Q
// (368 rows, 47KB LDS) staged once, all 23 S i-tiles gathered per-wave
// (3/wave), full q-max in-block -> direct f32 store (no atomics/decode).
// LDS 48.6KB -> 3 blocks/CU; 600 blocks <= 768 slots -> single generation.
// Per-thread state identical to R7 (measured VGPR 40) -> (512,6)'s 85-VGPR
// cap is safe; WRITE_SIZE is the spill tripwire.
// LDS row layout: pitch 64 bf16 (128B), 16B-granule XOR swizzle (g ^ (m&7));
// bank-uniform for b128 writes and b128 fragment reads (proven R1/R2).

// Stage one Q row: 64 strided floats in 2 rounds of 32, bf16-pack, swizzled
// b128 writes; returns rsqrt(sumsq).
__device__ __forceinline__ float stage_row32(const float* __restrict__ gp,
                                             unsigned short* __restrict__ dst,
                                             int sw) {
  float ss = 0.f;
  #pragma unroll
  for (int h = 0; h < 2; ++h) {
    float v[32];
    #pragma unroll
    for (int j = 0; j < 32; ++j) v[j] = gp[(h * 32 + j) * WW];  // coalesced
    #pragma unroll
    for (int c = 0; c < 4; ++c) {
      unsigned int u[4];
      #pragma unroll
      for (int jj = 0; jj < 4; ++jj) {
        float x = v[c * 8 + 2 * jj], y = v[c * 8 + 2 * jj + 1];
        ss += x * x + y * y;
        __hip_bfloat162 b2 = __float22bfloat162_rn(make_float2(x, y));
        u[jj] = *(unsigned int*)&b2;
      }
      *(uint4*)&dst[((h * 4 + c) ^ sw) * 8] = make_uint4(u[0], u[1], u[2], u[3]);
    }
  }
  return rsqrtf(ss);
}

__device__ __forceinline__ void zero_row(unsigned short* __restrict__ dst) {
  #pragma unroll
  for (int c = 0; c < 8; ++c)
    *(uint4*)&dst[c * 8] = make_uint4(0u, 0u, 0u, 0u);
}

// convert 16 gathered floats -> one A fragment pair + own-lane sumsq part
__device__ __forceinline__ void packA(const float* w, short8& af0, short8& af1,
                                      float& ssout) {
  unsigned int u[8];
  float ss = 0.f;
  #pragma unroll
  for (int jj = 0; jj < 8; ++jj) {
    float x = w[2 * jj], y = w[2 * jj + 1];
    ss += x * x + y * y;
    __hip_bfloat162 b2 = __float22bfloat162_rn(make_float2(x, y));
    u[jj] = *(unsigned int*)&b2;
  }
  uint4 t0 = make_uint4(u[0], u[1], u[2], u[3]);
  uint4 t1 = make_uint4(u[4], u[5], u[6], u[7]);
  af0 = *(short8*)&t0;
  af1 = *(short8*)&t1;
  ssout = ss;
}

__device__ __forceinline__ void epilogueStore(f32x4 mx, float invA, int tileBase,
                                              int quad, int l15,
                                              float* __restrict__ outb) {
  #pragma unroll
  for (int d = 1; d < 16; d <<= 1) {
    #pragma unroll
    for (int r = 0; r < 4; ++r) mx[r] = fmaxf(mx[r], __shfl_xor(mx[r], d));
  }
  const float iv0 = __shfl(invA, 4 * quad + 0);
  const float iv1 = __shfl(invA, 4 * quad + 1);
  const float iv2 = __shfl(invA, 4 * quad + 2);
  const float iv3 = __shfl(invA, 4 * quad + 3);
  if (l15 == 0) {
    const int mb = tileBase + 4 * quad;
    if (mb + 0 < WW) outb[mb + 0] = mx[0] * iv0;
    if (mb + 1 < WW) outb[mb + 1] = mx[1] * iv1;
    if (mb + 2 < WW) outb[mb + 2] = mx[2] * iv2;
    if (mb + 3 < WW) outb[mb + 3] = mx[3] * iv3;
  }
}

__global__ __launch_bounds__(NTHR, 6) void cossim_max_kernel(
    const float* __restrict__ support, const float* __restrict__ query,
    float* __restrict__ out)
{
  __shared__ __align__(16) unsigned short Q_sh[NQR * CCH];  // 47104 B
  __shared__ float inv_q[NQR];                              //  1472 B -> 48576

  const int tid  = threadIdx.x;
  const int lane = tid & 63;
  const int wv   = tid >> 6;     // 0..7
  const int l15  = lane & 15;
  const int quad = lane >> 4;

  const int bs = (int)blockIdx.x;           // one block per bs; no reuse
  const float* sg = support + (size_t)bs * WWC;
  const float* qg = query   + (size_t)bs * WWC;

  // ---- Q staging: threads 0..367, one row each (2 wide rounds) ----
  if (tid < NQR) {
    if (tid < WW) {
      inv_q[tid] = stage_row32(qg + tid, &Q_sh[tid * CCH], tid & 7);
    } else {                     // rows 361..367: read by tile 22 -> zero
      zero_row(&Q_sh[tid * CCH]);
      inv_q[tid] = 0.f;
    }
  }

  // ---- A fragments: 3 i-tiles/wave (tiles 3wv..3wv+2; wave7 tile 23 dead) ----
  short8 af[3][2]; float invA[3];
  {
    const int iG0 = 16 * (3 * wv + 0) + l15;
    const int iG1 = 16 * (3 * wv + 1) + l15;
    const int iG2 = 16 * (3 * wv + 2) + l15;
    const bool v0 = iG0 < WW, v1 = iG1 < WW, v2 = iG2 < WW;
    float ss0, ss1, ss2;
    {
      float w[32];
      const float* s0 = sg + iG0;
      const float* s1 = sg + iG1;
      if (v0) {
        #pragma unroll
        for (int j = 0; j < 8; ++j) w[j]     = s0[(8 * quad + j) * WW];
        #pragma unroll
        for (int j = 0; j < 8; ++j) w[8 + j] = s0[(32 + 8 * quad + j) * WW];
      } else {
        #pragma unroll
        for (int j = 0; j < 16; ++j) w[j] = 0.f;
      }
      if (v1) {
        #pragma unroll
        for (int j = 0; j < 8; ++j) w[16 + j] = s1[(8 * quad + j) * WW];
        #pragma unroll
        for (int j = 0; j < 8; ++j) w[24 + j] = s1[(32 + 8 * quad + j) * WW];
      } else {
        #pragma unroll
        for (int j = 0; j < 16; ++j) w[16 + j] = 0.f;
      }
      packA(&w[0],  af[0][0], af[0][1], ss0);
      packA(&w[16], af[1][0], af[1][1], ss1);
    }
    {
      float w[16];
      const float* s2 = sg + iG2;
      if (v2) {
        #pragma unroll
        for (int j = 0; j < 8; ++j) w[j]     = s2[(8 * quad + j) * WW];
        #pragma unroll
        for (int j = 0; j < 8; ++j) w[8 + j] = s2[(32 + 8 * quad + j) * WW];
      } else {
        #pragma unroll
        for (int j = 0; j < 16; ++j) w[j] = 0.f;
      }
      packA(&w[0], af[2][0], af[2][1], ss2);
    }
    ss0 += __shfl_xor(ss0, 16); ss0 += __shfl_xor(ss0, 32);
    ss1 += __shfl_xor(ss1, 16); ss1 += __shfl_xor(ss1, 32);
    ss2 += __shfl_xor(ss2, 16); ss2 += __shfl_xor(ss2, 32);
    invA[0] = v0 ? rsqrtf(ss0) : 0.f;
    invA[1] = v1 ? rsqrtf(ss1) : 0.f;
    invA[2] = v2 ? rsqrtf(ss2) : 0.f;
  }

  __syncthreads();

  // ---- compute: all 23 q-tiles from swizzled LDS; 3 MFMA pairs / B-frag ----
  const int boff0 = l15 * CCH + ((quad       ^ (l15 & 7)) * 8);
  const int boff1 = l15 * CCH + (((4 + quad) ^ (l15 & 7)) * 8);
  // tile 22 covers q-rows 352+l15 -> pad for l15 >= 9
  const float lastbias = (l15 < 9) ? 0.f : -1e30f;

  f32x4 mx0 = {-3e38f, -3e38f, -3e38f, -3e38f};
  f32x4 mx1 = mx0, mx2 = mx0;

  for (int t = 0; t < NT; ++t) {
    const int nb = t * 16 * CCH;
    short8 b0 = *(const short8*)&Q_sh[nb + boff0];
    short8 b1 = *(const short8*)&Q_sh[nb + boff1];
    const float qs = inv_q[t * 16 + l15];
    const float bb = (t == NT - 1) ? lastbias : 0.f;
    f32x4 a0 = {0.f, 0.f, 0.f, 0.f}, a1 = a0, a2 = a0;
    __builtin_amdgcn_s_setprio(1);
    a0 = __builtin_amdgcn_mfma_f32_16x16x32_bf16(af[0][0], b0, a0, 0, 0, 0);
    a0 = __builtin_amdgcn_mfma_f32_16x16x32_bf16(af[0][1], b1, a0, 0, 0, 0);
    a1 = __builtin_amdgcn_mfma_f32_16x16x32_bf16(af[1][0], b0, a1, 0, 0, 0);
    a1 = __builtin_amdgcn_mfma_f32_16x16x32_bf16(af[1][1], b1, a1, 0, 0, 0);
    a2 = __builtin_amdgcn_mfma_f32_16x16x32_bf16(af[2][0], b0, a2, 0, 0, 0);
    a2 = __builtin_amdgcn_mfma_f32_16x16x32_bf16(af[2][1], b1, a2, 0, 0, 0);
    __builtin_amdgcn_s_setprio(0);
    #pragma unroll
    for (int r = 0; r < 4; ++r) {
      mx0[r] = fmaxf(mx0[r], a0[r] * qs + bb);
      mx1[r] = fmaxf(mx1[r], a1[r] * qs + bb);
      mx2[r] = fmaxf(mx2[r], a2[r] * qs + bb);
    }
  }

  float* outb = out + (size_t)bs * WW;
  {
    const int tb0 = 16 * (3 * wv + 0);
    const int tb1 = 16 * (3 * wv + 1);
    const int tb2 = 16 * (3 * wv + 2);
    if (tb0 < WW) epilogueStore(mx0, invA[0], tb0, quad, l15, outb);
    if (tb1 < WW) epilogueStore(mx1, invA[1], tb1, quad, l15, outb);
    if (tb2 < WW) epilogueStore(mx2, invA[2], tb2, quad, l15, outb);
  }
}

extern "C" void kernel_launch(void* const* d_in, const int* in_sizes, int n_in,
                              void* d_out, int out_size, void* d_ws, size_t ws_size,
                              hipStream_t stream) {
  const float* support = (const float*)d_in[0];
  const float* query   = (const float*)d_in[1];
  float* out = (float*)d_out;
  dim3 grid(600), block(NTHR);
  hipLaunchKernelGGL(cossim_max_kernel, grid, block, 0, stream,
                     support, query, out);
}